// Round 18
// baseline (4362.107 us; speedup 1.0000x reference)
//
#include <hip/hip_runtime.h>
#include <hip/hip_bf16.h>

// ---------------- problem constants ----------------
#define BB 8192
#define TT 32
#define DD 12
#define ZZ 128
#define HE 512
#define HD 1024
#define KE 576    // 512 + 12 + pad -> 9 x 64
#define KD 1088   // 1024 + 12 + pad -> 17 x 64

typedef unsigned short u16;
typedef __attribute__((ext_vector_type(8))) short bf16x8;
typedef __attribute__((ext_vector_type(4))) float f32x4;

__device__ __forceinline__ u16 f2bf(float f) {
    __hip_bfloat16 h = __float2bfloat16(f);
    return *reinterpret_cast<u16*>(&h);
}
__device__ __forceinline__ float bf2f(u16 u) {
    __hip_bfloat16 h;
    *reinterpret_cast<u16*>(&h) = u;
    return __bfloat162float(h);
}
__device__ __forceinline__ float sigmf(float x) { return 1.f / (1.f + __expf(-x)); }
__device__ __forceinline__ float tanh_(float x) {
    float ax = fabsf(x);
    float e = __expf(-2.f * ax);
    float t = (1.f - e) / (1.f + e);
    return copysignf(t, x);
}

__device__ __forceinline__ void gload_lds16(const void* g, void* l) {
    __builtin_amdgcn_global_load_lds(
        (const __attribute__((address_space(1))) void*)g,
        (__attribute__((address_space(3))) void*)l,
        16, 0, 0);
}

// ============================================================================
// KERNEL A (round-16 proven; decoder best: 85.2us, MfmaUtil 38%, ~2.8
// blocks/CU): 128x128, BK=64 single-buffer, XOR-swizzled LDS (conflicts==0),
// fused LSTM epilogue with PERMUTED c-state.
// Swizzle (rule #21 both-sides): LDS phys (row r, slot sp) holds global
// k-slot sp^(r&7); stage linear dest + inverse-swizzled global src slot
// (lane&7)^(lane>>3); read phys slot (ks*4+(lane>>4))^(lane&7).
// MODE 0: plain fp32 C.  MODE 2: decoder LSTM (stage x[t]).
// ============================================================================
template<int MODE>
__global__ __launch_bounds__(256, 4)
void gemm128(const u16* __restrict__ A, const u16* __restrict__ W,
             float* __restrict__ C, int N, int K, int H,
             float* __restrict__ Cst, u16* __restrict__ Aout,
             const float* __restrict__ bias, const int* __restrict__ lens,
             u16* __restrict__ HN, const float* __restrict__ X, int t)
{
    __shared__ u16 As[128 * 64];
    __shared__ u16 Ws[128 * 64];
    const int tid  = threadIdx.x;
    const int lane = tid & 63;
    const int wave = tid >> 6;
    const int wm = wave >> 1, wn = wave & 1;
    const int bm = blockIdx.x * 128;
    const int bn = blockIdx.y * 128;

    f32x4 acc[4][4] = {};

    const int lrow = lane >> 3;                       // 0..7
    const int lcol = ((lane & 7) ^ lrow) * 8;         // inverse-swizzled src slot

    for (int kt = 0; kt < K; kt += 64) {
#pragma unroll
        for (int c2 = 0; c2 < 4; ++c2) {
            const int chunk = wave * 4 + c2;          // 0..15
            const int row = chunk * 8 + lrow;         // 0..127 ; row&7 == lrow
            gload_lds16(A + (size_t)(bm + row) * K + kt + lcol, &As[chunk * 512]);
            gload_lds16(W + (size_t)(bn + row) * K + kt + lcol, &Ws[chunk * 512]);
        }
        __syncthreads();
#pragma unroll
        for (int ks = 0; ks < 2; ++ks) {
            bf16x8 af[4], wf[4];
            const int ko = (((ks * 4) + (lane >> 4)) ^ (lane & 7)) * 8;  // swizzled
            const int rA = wm * 64 + (lane & 15);
            const int rW = wn * 64 + (lane & 15);
#pragma unroll
            for (int i = 0; i < 4; ++i)
                af[i] = *(const bf16x8*)&As[(rA + i * 16) * 64 + ko];
#pragma unroll
            for (int i = 0; i < 4; ++i)
                wf[i] = *(const bf16x8*)&Ws[(rW + i * 16) * 64 + ko];
#pragma unroll
            for (int i = 0; i < 4; ++i)
#pragma unroll
                for (int j = 0; j < 4; ++j)
                    acc[i][j] = __builtin_amdgcn_mfma_f32_16x16x32_bf16(
                        af[i], wf[j], acc[i][j], 0, 0, 0);
        }
        __syncthreads();
    }

    if (MODE == 0) {
        const int r0 = bm + wm * 64 + (lane >> 4) * 4;
        const int c0 = bn + wn * 64 + (lane & 15);
#pragma unroll
        for (int i = 0; i < 4; ++i)
#pragma unroll
            for (int j = 0; j < 4; ++j) {
                float* Cp = C + (size_t)(r0 + i * 16) * N + c0 + j * 16;
#pragma unroll
                for (int q = 0; q < 4; ++q)
                    Cp[(size_t)q * N] = acc[i][j][q];
            }
    } else {
        const int hcol = ((bn >> 6) + wn) * 16 + (lane & 15);
        const int hb   = (bn >> 6) + wn;
        const int hl   = lane & 15;
        float* csb = Cst + ((size_t)hb * BB) * 16 + hl;   // permuted c-state
        const float bI = bias[hcol];
        const float bF = bias[H + hcol];
        const float bG = bias[2 * H + hcol];
        const float bO = bias[3 * H + hcol];
#pragma unroll
        for (int i = 0; i < 4; ++i) {
            const int rbase = bm + wm * 64 + i * 16 + (lane >> 4) * 4;
#pragma unroll
            for (int q = 0; q < 4; ++q) {
                const int r = rbase + q;
                float iv = sigmf(acc[i][0][q] + bI);
                float fv = sigmf(acc[i][1][q] + bF);
                float gv = tanh_(acc[i][2][q] + bG);
                float ov = sigmf(acc[i][3][q] + bO);
                float cn = fv * csb[(size_t)r * 16] + iv * gv;
                float h  = ov * tanh_(cn);
                csb[(size_t)r * 16] = cn;
                Aout[(size_t)r * K + hcol] = f2bf(h);
            }
        }
        const int tx = t;   // decoder stages x[t]
        if (bn == 0 && tx < TT) {
            for (int ii = tid; ii < 128 * DD; ii += 256) {
                const int rr = ii / DD, d = ii - rr * DD;
                const int r = bm + rr;
                Aout[(size_t)r * K + H + d] =
                    f2bf(X[((size_t)r * TT + tx) * DD + d]);
            }
        }
    }
}

// ============================================================================
// KERNEL B (round-17 proven; encoder best): 128x256 block, BK=64, 4 waves
// (2Mx2N) of 64x128, same swizzle, fused encoder LSTM epilogue (+hn capture,
// stages x[t+1]).  48KB LDS, __launch_bounds__(256,2).
// Gate map: frag j -> quad q=j>>2, gate=j&3; hb=(bn>>6)+wn*2+q.
// ============================================================================
__global__ __launch_bounds__(256, 2)
void gemm256e(const u16* __restrict__ A, const u16* __restrict__ W,
              int K, int H,
              float* __restrict__ Cst, u16* __restrict__ Aout,
              const float* __restrict__ bias, const int* __restrict__ lens,
              u16* __restrict__ HN, const float* __restrict__ X, int t)
{
    __shared__ u16 As[128 * 64];
    __shared__ u16 Ws[256 * 64];
    const int tid  = threadIdx.x;
    const int lane = tid & 63;
    const int wave = tid >> 6;
    const int wm = wave >> 1, wn = wave & 1;
    const int bm = blockIdx.x * 128;
    const int bn = blockIdx.y * 256;

    f32x4 acc[4][8] = {};

    const int lrow = lane >> 3;
    const int lcol = ((lane & 7) ^ lrow) * 8;

    for (int kt = 0; kt < K; kt += 64) {
#pragma unroll
        for (int c2 = 0; c2 < 4; ++c2) {
            const int chunk = wave * 4 + c2;
            const int row = chunk * 8 + lrow;
            gload_lds16(A + (size_t)(bm + row) * K + kt + lcol, &As[chunk * 512]);
        }
#pragma unroll
        for (int c8 = 0; c8 < 8; ++c8) {
            const int chunk = wave * 8 + c8;
            const int row = chunk * 8 + lrow;
            gload_lds16(W + (size_t)(bn + row) * K + kt + lcol, &Ws[chunk * 512]);
        }
        __syncthreads();
#pragma unroll
        for (int ks = 0; ks < 2; ++ks) {
            bf16x8 af[4], wf[8];
            const int ko = (((ks * 4) + (lane >> 4)) ^ (lane & 7)) * 8;
            const int rA = wm * 64 + (lane & 15);
            const int rW = wn * 128 + (lane & 15);
#pragma unroll
            for (int i = 0; i < 4; ++i)
                af[i] = *(const bf16x8*)&As[(rA + i * 16) * 64 + ko];
#pragma unroll
            for (int j = 0; j < 8; ++j)
                wf[j] = *(const bf16x8*)&Ws[(rW + j * 16) * 64 + ko];
#pragma unroll
            for (int i = 0; i < 4; ++i)
#pragma unroll
                for (int j = 0; j < 8; ++j)
                    acc[i][j] = __builtin_amdgcn_mfma_f32_16x16x32_bf16(
                        af[i], wf[j], acc[i][j], 0, 0, 0);
        }
        __syncthreads();
    }

    const int hl = lane & 15;
#pragma unroll
    for (int q = 0; q < 2; ++q) {
        const int hb   = (bn >> 6) + wn * 2 + q;
        const int hcol = hb * 16 + hl;
        float* csb = Cst + ((size_t)hb * BB) * 16 + hl;
        const float bI = bias[hcol];
        const float bF = bias[H + hcol];
        const float bG = bias[2 * H + hcol];
        const float bO = bias[3 * H + hcol];
#pragma unroll
        for (int i = 0; i < 4; ++i) {
            const int rbase = bm + wm * 64 + i * 16 + (lane >> 4) * 4;
#pragma unroll
            for (int qq = 0; qq < 4; ++qq) {
                const int r = rbase + qq;
                float iv = sigmf(acc[i][q * 4 + 0][qq] + bI);
                float fv = sigmf(acc[i][q * 4 + 1][qq] + bF);
                float gv = tanh_(acc[i][q * 4 + 2][qq] + bG);
                float ov = sigmf(acc[i][q * 4 + 3][qq] + bO);
                float cn = fv * csb[(size_t)r * 16] + iv * gv;
                float h  = ov * tanh_(cn);
                csb[(size_t)r * 16] = cn;
                Aout[(size_t)r * K + hcol] = f2bf(h);
                int L = lens[r]; L = (L < 1) ? 1 : (L > TT ? TT : L);
                if (t == L - 1) HN[(size_t)r * H + hcol] = f2bf(h);
            }
        }
    }
    const int tx = t + 1;   // encoder stages x[t+1]
    if (bn == 0 && tx < TT) {
        for (int ii = tid; ii < 128 * DD; ii += 256) {
            const int rr = ii / DD, d = ii - rr * DD;
            const int r = bm + rr;
            Aout[(size_t)r * K + H + d] = f2bf(X[((size_t)r * TT + tx) * DD + d]);
        }
    }
}

// ---------------- gate-interleaved weight concat ----------------
__global__ void prep_wg(const float* __restrict__ Whh, const float* __restrict__ Wih,
                        u16* __restrict__ dst, int H, int Kc, int total)
{
    int idx = blockIdx.x * 256 + threadIdx.x;
    if (idx >= total) return;
    int np = idx / Kc, k = idx - np * Kc;
    int jblk = np >> 6, rem = np & 63;
    int gate = rem >> 4, jl = rem & 15;
    int j = jblk * 16 + jl;
    int srow = gate * H + j;
    float v = 0.f;
    if (k < H) v = Whh[(size_t)srow * H + k];
    else if (k < H + DD) v = Wih[srow * DD + (k - H)];
    dst[idx] = f2bf(v);
}

__global__ void prep_cat(const float* __restrict__ W0, const float* __restrict__ W1,
                         u16* __restrict__ dst, int rows0, int K, int total)
{
    int idx = blockIdx.x * 256 + threadIdx.x;
    if (idx >= total) return;
    int n = idx / K, k = idx - n * K;
    float v = (n < rows0) ? W0[(size_t)n * K + k] : W1[(size_t)(n - rows0) * K + k];
    dst[idx] = f2bf(v);
}

__global__ void prep_bf(const float* __restrict__ src, u16* __restrict__ dst, int total)
{
    int idx = blockIdx.x * 256 + threadIdx.x;
    if (idx < total) dst[idx] = f2bf(src[idx]);
}

__global__ void init_enc(u16* __restrict__ A, float* __restrict__ c, const float* __restrict__ x)
{
    int idx = blockIdx.x * 256 + threadIdx.x;   // BB*KE
    int b = idx / KE, j = idx - b * KE;
    u16 v = 0;
    if (j >= HE && j < HE + DD) v = f2bf(x[(size_t)b * (TT * DD) + (j - HE)]);
    A[idx] = v;
    if (j < HE) c[(size_t)b * HE + j] = 0.f;
}

__global__ void zero_pads(u16* __restrict__ A, int ldK, int lo, int n, int total)
{
    int idx = blockIdx.x * 256 + threadIdx.x;
    if (idx >= total) return;
    int b = idx / n, j = idx - b * n;
    A[(size_t)b * ldK + lo + j] = 0;
}

__global__ void z_comp(const float* __restrict__ MV, const float* __restrict__ bmu,
                       const float* __restrict__ blv, const float* __restrict__ eps,
                       float* __restrict__ out, u16* __restrict__ Zbf)
{
    int idx = blockIdx.x * 256 + threadIdx.x;   // BB*ZZ
    int b = idx >> 7, zc = idx & (ZZ - 1);
    float mu = MV[(size_t)b * 256 + zc] + bmu[zc];
    float lv = MV[(size_t)b * 256 + ZZ + zc] + blv[zc];
    float z = mu + eps[idx] * __expf(0.5f * lv);
    const size_t XR = (size_t)BB * TT * DD;
    out[XR + idx] = mu;
    out[XR + (size_t)BB * ZZ + idx] = lv;
    out[XR + 2 * (size_t)BB * ZZ + idx] = z;
    Zbf[idx] = f2bf(z);
}

// c written in PERMUTED layout c[j>>4][b][j&15]
__global__ void hc_init(const float* __restrict__ HC, const float* __restrict__ bh0,
                        const float* __restrict__ bc0, u16* __restrict__ A,
                        float* __restrict__ c)
{
    int idx = blockIdx.x * 256 + threadIdx.x;   // BB*HD
    int b = idx >> 10, j = idx & (HD - 1);
    float h0 = tanh_(HC[(size_t)b * 2048 + j] + bh0[j]);
    float c0 = tanh_(HC[(size_t)b * 2048 + HD + j] + bc0[j]);
    A[(size_t)b * KD + j] = f2bf(h0);
    c[(((size_t)(j >> 4)) * BB + b) * 16 + (j & 15)] = c0;
}

__global__ void init_dec(u16* __restrict__ A, const float* __restrict__ st)
{
    int idx = blockIdx.x * 256 + threadIdx.x;   // BB*64
    int b = idx >> 6, j = idx & 63;
    A[(size_t)b * KD + HD + j] = (j < DD) ? f2bf(st[j]) : (u16)0;
}

// ---------------- output projection, thread-per-(row,d), PAIRED ------------
__global__ __launch_bounds__(256, 8)
void outproj_pd(const u16* __restrict__ H0, const u16* __restrict__ H1,
                const u16* __restrict__ Wb, const float* __restrict__ bout,
                float* __restrict__ xr, int t)
{
    int gid = blockIdx.x * 256 + threadIdx.x;   // BB*16
    int b = gid >> 4;
    int d = gid & 15;
    const bool act = (d < DD);
    const int dc = act ? d : 0;
    const u16* h0 = H0 + (size_t)b * KD;
    const u16* h1 = H1 + (size_t)b * KD;
    const u16* w  = Wb + dc * HD;
    float a0 = 0.f, a1 = 0.f;
    for (int k = 0; k < HD; k += 8) {
        bf16x8 wv = *(const bf16x8*)&w[k];
        bf16x8 v0 = *(const bf16x8*)&h0[k];
        bf16x8 v1 = *(const bf16x8*)&h1[k];
#pragma unroll
        for (int q = 0; q < 8; ++q) {
            float wf = bf2f((u16)wv[q]);
            a0 += bf2f((u16)v0[q]) * wf;
            a1 += bf2f((u16)v1[q]) * wf;
        }
    }
    if (act) {
        xr[((size_t)b * TT + t) * DD + d]     = a0 + bout[d];
        xr[((size_t)b * TT + t + 1) * DD + d] = a1 + bout[d];
    }
}

// ---------------- launch ----------------
extern "C" void kernel_launch(void* const* d_in, const int* in_sizes, int n_in,
                              void* d_out, int out_size, void* d_ws, size_t ws_size,
                              hipStream_t stream)
{
    const float* x    = (const float*)d_in[0];
    const int*   lens = (const int*)d_in[1];
    const float* eps  = (const float*)d_in[2];
    const float* Wihe = (const float*)d_in[3];
    const float* Whhe = (const float*)d_in[4];
    const float* be   = (const float*)d_in[5];
    const float* Wmu  = (const float*)d_in[6];
    const float* bmu  = (const float*)d_in[7];
    const float* Wlv  = (const float*)d_in[8];
    const float* blv  = (const float*)d_in[9];
    const float* Wh0  = (const float*)d_in[10];
    const float* bh0  = (const float*)d_in[11];
    const float* Wc0  = (const float*)d_in[12];
    const float* bc0  = (const float*)d_in[13];
    const float* st   = (const float*)d_in[14];
    const float* Wihd = (const float*)d_in[15];
    const float* Whhd = (const float*)d_in[16];
    const float* bd   = (const float*)d_in[17];
    const float* Wout = (const float*)d_in[18];
    const float* bout = (const float*)d_in[19];
    float* out = (float*)d_out;

    char* ws = (char*)d_ws;
    size_t o = 0;
    u16*   WCE = (u16*)(ws + o); o += (size_t)2048 * KE * 2;   // 2,359,296
    u16*   WCD = (u16*)(ws + o); o += (size_t)4096 * KD * 2;   // 8,912,896
    u16*   WMV = (u16*)(ws + o); o += (size_t)256 * 512 * 2;   // 262,144
    u16*   WHC = (u16*)(ws + o); o += (size_t)2048 * 128 * 2;  // 524,288
    u16*   WOB = (u16*)(ws + o); o += 32768;
    u16*   AE0 = (u16*)(ws + o); o += (size_t)BB * KE * 2;     // 9,437,184
    u16*   AE1 = (u16*)(ws + o); o += (size_t)BB * KE * 2;
    u16*   AD0 = (u16*)(ws + o); o += (size_t)BB * KD * 2;     // 17,825,792
    u16*   AD1 = (u16*)(ws + o); o += (size_t)BB * KD * 2;
    float* CE  = (float*)(ws + o); o += (size_t)BB * HE * 4;   // 16,777,216
    float* CD  = (float*)(ws + o); o += (size_t)BB * HD * 4;   // 33,554,432
    u16*   HNb = (u16*)(ws + o); o += (size_t)BB * HE * 2;     // 8,388,608
    float* MV  = (float*)(ws + o); o += (size_t)BB * 256 * 4;  // 8,388,608
    u16*   Zbf = (u16*)(ws + o); o += (size_t)BB * ZZ * 2;     // 2,097,152
    float* HC  = (float*)(ws + o); o += (size_t)BB * 2048 * 4; // 67,108,864
    // total ~203 MB

    prep_wg<<<(2048 * KE + 255) / 256, 256, 0, stream>>>(Whhe, Wihe, WCE, HE, KE, 2048 * KE);
    prep_wg<<<(4096 * KD + 255) / 256, 256, 0, stream>>>(Whhd, Wihd, WCD, HD, KD, 4096 * KD);
    prep_cat<<<(256 * 512 + 255) / 256, 256, 0, stream>>>(Wmu, Wlv, WMV, ZZ, HE, 256 * 512);
    prep_cat<<<(2048 * 128 + 255) / 256, 256, 0, stream>>>(Wh0, Wc0, WHC, HD, ZZ, 2048 * 128);
    prep_bf<<<(12 * HD + 255) / 256, 256, 0, stream>>>(Wout, WOB, 12 * HD);
    init_enc<<<(BB * KE) / 256, 256, 0, stream>>>(AE0, CE, x);
    zero_pads<<<(BB * 52 + 255) / 256, 256, 0, stream>>>(AE1, KE, HE + DD, 52, BB * 52);
    zero_pads<<<(BB * 52 + 255) / 256, 256, 0, stream>>>(AD1, KD, HD + DD, 52, BB * 52);

    u16* AE[2] = {AE0, AE1};
    for (int t = 0; t < TT; ++t) {
        gemm256e<<<dim3(BB / 128, 2048 / 256), 256, 0, stream>>>(
            AE[t & 1], WCE, KE, HE, CE, AE[1 - (t & 1)], be, lens, HNb, x, t);
    }

    gemm128<0><<<dim3(BB / 128, 256 / 128), 256, 0, stream>>>(
        HNb, WMV, MV, 256, 512, 0, nullptr, nullptr, nullptr, nullptr, nullptr, nullptr, 0);
    z_comp<<<(BB * ZZ) / 256, 256, 0, stream>>>(MV, bmu, blv, eps, out, Zbf);
    gemm128<0><<<dim3(BB / 128, 2048 / 128), 256, 0, stream>>>(
        Zbf, WHC, HC, 2048, 128, 0, nullptr, nullptr, nullptr, nullptr, nullptr, nullptr, 0);
    hc_init<<<(BB * HD) / 256, 256, 0, stream>>>(HC, bh0, bc0, AD0, CD);
    init_dec<<<(BB * 64) / 256, 256, 0, stream>>>(AD0, st);

    u16* AD[2] = {AD0, AD1};
    for (int t = 0; t < TT; t += 2) {
        gemm128<2><<<dim3(BB / 128, 4096 / 128), 256, 0, stream>>>(
            AD[t & 1], WCD, nullptr, 4096, KD, HD, CD, AD[1 - (t & 1)],
            bd, nullptr, nullptr, x, t);
        gemm128<2><<<dim3(BB / 128, 4096 / 128), 256, 0, stream>>>(
            AD[1 - (t & 1)], WCD, nullptr, 4096, KD, HD, CD, AD[t & 1],
            bd, nullptr, nullptr, x, t + 1);
        outproj_pd<<<(BB * 16) / 256, 256, 0, stream>>>(
            AD[1 - (t & 1)], AD[t & 1], WOB, bout, out, t);
    }
}

// Round 19
// 4293.465 us; speedup vs baseline: 1.0160x; 1.0160x over previous
//
#include <hip/hip_runtime.h>
#include <hip/hip_bf16.h>

// ---------------- problem constants ----------------
#define BB 8192
#define TT 32
#define DD 12
#define ZZ 128
#define HE 512
#define HD 1024
#define KE 576    // 512 + 12 + pad -> 9 x 64
#define KD 1088   // 1024 + 12 + pad -> 17 x 64

typedef unsigned short u16;
typedef __attribute__((ext_vector_type(8))) short bf16x8;
typedef __attribute__((ext_vector_type(4))) float f32x4;

__device__ __forceinline__ u16 f2bf(float f) {
    __hip_bfloat16 h = __float2bfloat16(f);
    return *reinterpret_cast<u16*>(&h);
}
__device__ __forceinline__ float bf2f(u16 u) {
    __hip_bfloat16 h;
    *reinterpret_cast<u16*>(&h) = u;
    return __bfloat162float(h);
}
__device__ __forceinline__ float sigmf(float x) { return 1.f / (1.f + __expf(-x)); }
__device__ __forceinline__ float tanh_(float x) {
    float ax = fabsf(x);
    float e = __expf(-2.f * ax);
    float t = (1.f - e) / (1.f + e);
    return copysignf(t, x);
}

__device__ __forceinline__ void gload_lds16(const void* g, void* l) {
    __builtin_amdgcn_global_load_lds(
        (const __attribute__((address_space(1))) void*)g,
        (__attribute__((address_space(3))) void*)l,
        16, 0, 0);
}

// ============================================================================
// ROUND-17 CONFIG (best measured total: 4.305 ms).
// 128x256 GEMM block, BK=64 single-buffer, 4 waves (2Mx2N) of 64x128 each.
// 34.4 B/KFLOP DS traffic; 48KB LDS -> 2 blocks/CU at (256,2).
// Swizzle (rule #21 both-sides, verified conflicts==0): LDS phys (row r,
// 16B slot sp) holds global k-slot sp^(r&7); stage linear dest
// (row=chunk*8+(lane>>3), slot=lane&7) with inverse-swizzled global src slot
// (lane&7)^(lane>>3); read phys slot (ks*4+(lane>>4))^(lane&7).
// Gate map: frag j -> quad q=j>>2, gate=j&3; hb=(bn>>6)+wn*2+q (prep_wg
// interleave).  c-state PERMUTED: Cst[hb][r][hl] fp32 (contiguous 64B
// segments per (i,q) in the epilogue).
// MODE 0: plain fp32 C.  MODE 1: encoder LSTM (+hn capture, stage x[t+1]).
// MODE 2: decoder LSTM (stage x[t]).  N must be a multiple of 256.
// ============================================================================
template<int MODE>
__global__ __launch_bounds__(256, 2)
void gemm_fused(const u16* __restrict__ A, const u16* __restrict__ W,
                float* __restrict__ C, int N, int K, int H,
                float* __restrict__ Cst, u16* __restrict__ Aout,
                const float* __restrict__ bias, const int* __restrict__ lens,
                u16* __restrict__ HN, const float* __restrict__ X, int t)
{
    __shared__ u16 As[128 * 64];
    __shared__ u16 Ws[256 * 64];
    const int tid  = threadIdx.x;
    const int lane = tid & 63;
    const int wave = tid >> 6;
    const int wm = wave >> 1, wn = wave & 1;
    const int bm = blockIdx.x * 128;
    const int bn = blockIdx.y * 256;

    f32x4 acc[4][8] = {};

    const int lrow = lane >> 3;                       // 0..7
    const int lcol = ((lane & 7) ^ lrow) * 8;         // inverse-swizzled src slot

    for (int kt = 0; kt < K; kt += 64) {
        // stage A: 16 chunks of 8 rows (4 per wave)
#pragma unroll
        for (int c2 = 0; c2 < 4; ++c2) {
            const int chunk = wave * 4 + c2;          // 0..15
            const int row = chunk * 8 + lrow;         // 0..127 ; row&7 == lrow
            gload_lds16(A + (size_t)(bm + row) * K + kt + lcol, &As[chunk * 512]);
        }
        // stage W: 32 chunks of 8 rows (8 per wave)
#pragma unroll
        for (int c8 = 0; c8 < 8; ++c8) {
            const int chunk = wave * 8 + c8;          // 0..31
            const int row = chunk * 8 + lrow;         // 0..255 ; row&7 == lrow
            gload_lds16(W + (size_t)(bn + row) * K + kt + lcol, &Ws[chunk * 512]);
        }
        __syncthreads();
#pragma unroll
        for (int ks = 0; ks < 2; ++ks) {
            bf16x8 af[4], wf[8];
            const int ko = (((ks * 4) + (lane >> 4)) ^ (lane & 7)) * 8;  // swizzled
            const int rA = wm * 64 + (lane & 15);
            const int rW = wn * 128 + (lane & 15);
#pragma unroll
            for (int i = 0; i < 4; ++i)
                af[i] = *(const bf16x8*)&As[(rA + i * 16) * 64 + ko];
#pragma unroll
            for (int j = 0; j < 8; ++j)
                wf[j] = *(const bf16x8*)&Ws[(rW + j * 16) * 64 + ko];
#pragma unroll
            for (int i = 0; i < 4; ++i)
#pragma unroll
                for (int j = 0; j < 8; ++j)
                    acc[i][j] = __builtin_amdgcn_mfma_f32_16x16x32_bf16(
                        af[i], wf[j], acc[i][j], 0, 0, 0);
        }
        __syncthreads();
    }

    if (MODE == 0) {
        // C/D layout: col = lane&15, row = (lane>>4)*4 + reg
        const int r0 = bm + wm * 64 + (lane >> 4) * 4;
#pragma unroll
        for (int i = 0; i < 4; ++i)
#pragma unroll
            for (int j = 0; j < 8; ++j) {
                float* Cp = C + (size_t)(r0 + i * 16) * N
                              + bn + wn * 128 + j * 16 + (lane & 15);
#pragma unroll
                for (int q = 0; q < 4; ++q)
                    Cp[(size_t)q * N] = acc[i][j][q];
            }
    } else {
        const int hl = lane & 15;
#pragma unroll
        for (int q = 0; q < 2; ++q) {                 // j-quad
            const int hb   = (bn >> 6) + wn * 2 + q;  // jblk
            const int hcol = hb * 16 + hl;
            float* csb = Cst + ((size_t)hb * BB) * 16 + hl;   // permuted c-state
            const float bI = bias[hcol];
            const float bF = bias[H + hcol];
            const float bG = bias[2 * H + hcol];
            const float bO = bias[3 * H + hcol];
#pragma unroll
            for (int i = 0; i < 4; ++i) {
                const int rbase = bm + wm * 64 + i * 16 + (lane >> 4) * 4;
#pragma unroll
                for (int qq = 0; qq < 4; ++qq) {
                    const int r = rbase + qq;
                    float iv = sigmf(acc[i][q * 4 + 0][qq] + bI);
                    float fv = sigmf(acc[i][q * 4 + 1][qq] + bF);
                    float gv = tanh_(acc[i][q * 4 + 2][qq] + bG);
                    float ov = sigmf(acc[i][q * 4 + 3][qq] + bO);
                    float cn = fv * csb[(size_t)r * 16] + iv * gv;
                    float h  = ov * tanh_(cn);
                    csb[(size_t)r * 16] = cn;
                    Aout[(size_t)r * K + hcol] = f2bf(h);
                    if (MODE == 1) {
                        int L = lens[r]; L = (L < 1) ? 1 : (L > TT ? TT : L);
                        if (t == L - 1) HN[(size_t)r * H + hcol] = f2bf(h);
                    }
                }
            }
        }
        // stage next-step x into Aout x-columns (one block column does it)
        const int tx = (MODE == 1) ? t + 1 : t;
        if (bn == 0 && tx < TT) {
            for (int ii = tid; ii < 128 * DD; ii += 256) {
                const int rr = ii / DD, d = ii - rr * DD;
                const int r = bm + rr;
                Aout[(size_t)r * K + H + d] =
                    f2bf(X[((size_t)r * TT + tx) * DD + d]);
            }
        }
    }
}

// ---------------- gate-interleaved weight concat ----------------
// n' = 64*(j>>4) + 16*gate + (j&15); row = [Whh[gate*H+j] | Wih[gate*H+j] | 0]
__global__ void prep_wg(const float* __restrict__ Whh, const float* __restrict__ Wih,
                        u16* __restrict__ dst, int H, int Kc, int total)
{
    int idx = blockIdx.x * 256 + threadIdx.x;
    if (idx >= total) return;
    int np = idx / Kc, k = idx - np * Kc;
    int jblk = np >> 6, rem = np & 63;
    int gate = rem >> 4, jl = rem & 15;
    int j = jblk * 16 + jl;
    int srow = gate * H + j;
    float v = 0.f;
    if (k < H) v = Whh[(size_t)srow * H + k];
    else if (k < H + DD) v = Wih[srow * DD + (k - H)];
    dst[idx] = f2bf(v);
}

// ---------------- plain stacked concat (bf16): [W0; W1] ----------------
__global__ void prep_cat(const float* __restrict__ W0, const float* __restrict__ W1,
                         u16* __restrict__ dst, int rows0, int K, int total)
{
    int idx = blockIdx.x * 256 + threadIdx.x;
    if (idx >= total) return;
    int n = idx / K, k = idx - n * K;
    float v = (n < rows0) ? W0[(size_t)n * K + k] : W1[(size_t)(n - rows0) * K + k];
    dst[idx] = f2bf(v);
}

__global__ void prep_bf(const float* __restrict__ src, u16* __restrict__ dst, int total)
{
    int idx = blockIdx.x * 256 + threadIdx.x;
    if (idx < total) dst[idx] = f2bf(src[idx]);
}

// ---------------- encoder init: h=0, x col = x[:,0,:], pad=0; c=0 ----------
__global__ void init_enc(u16* __restrict__ A, float* __restrict__ c, const float* __restrict__ x)
{
    int idx = blockIdx.x * 256 + threadIdx.x;   // BB*KE
    int b = idx / KE, j = idx - b * KE;
    u16 v = 0;
    if (j >= HE && j < HE + DD) v = f2bf(x[(size_t)b * (TT * DD) + (j - HE)]);
    A[idx] = v;
    if (j < HE) c[(size_t)b * HE + j] = 0.f;    // zero-fill, layout-agnostic
}

// ---------------- zero pad columns [lo, lo+n) of A[BB][ldK] ----------------
__global__ void zero_pads(u16* __restrict__ A, int ldK, int lo, int n, int total)
{
    int idx = blockIdx.x * 256 + threadIdx.x;
    if (idx >= total) return;
    int b = idx / n, j = idx - b * n;
    A[(size_t)b * ldK + lo + j] = 0;
}

// ---------------- z from MV = [mu | lv] fp32 ----------------
__global__ void z_comp(const float* __restrict__ MV, const float* __restrict__ bmu,
                       const float* __restrict__ blv, const float* __restrict__ eps,
                       float* __restrict__ out, u16* __restrict__ Zbf)
{
    int idx = blockIdx.x * 256 + threadIdx.x;   // BB*ZZ
    int b = idx >> 7, zc = idx & (ZZ - 1);
    float mu = MV[(size_t)b * 256 + zc] + bmu[zc];
    float lv = MV[(size_t)b * 256 + ZZ + zc] + blv[zc];
    float z = mu + eps[idx] * __expf(0.5f * lv);
    const size_t XR = (size_t)BB * TT * DD;
    out[XR + idx] = mu;
    out[XR + (size_t)BB * ZZ + idx] = lv;
    out[XR + 2 * (size_t)BB * ZZ + idx] = z;
    Zbf[idx] = f2bf(z);
}

// ---------------- decoder state init from HC = [h0pre | c0pre] -------------
// c written in PERMUTED layout c[j>>4][b][j&15]
__global__ void hc_init(const float* __restrict__ HC, const float* __restrict__ bh0,
                        const float* __restrict__ bc0, u16* __restrict__ A,
                        float* __restrict__ c)
{
    int idx = blockIdx.x * 256 + threadIdx.x;   // BB*HD
    int b = idx >> 10, j = idx & (HD - 1);
    float h0 = tanh_(HC[(size_t)b * 2048 + j] + bh0[j]);
    float c0 = tanh_(HC[(size_t)b * 2048 + HD + j] + bc0[j]);
    A[(size_t)b * KD + j] = f2bf(h0);
    c[(((size_t)(j >> 4)) * BB + b) * 16 + (j & 15)] = c0;
}

// ---------------- decoder x-col init: start token + zero pad ---------------
__global__ void init_dec(u16* __restrict__ A, const float* __restrict__ st)
{
    int idx = blockIdx.x * 256 + threadIdx.x;   // BB*64
    int b = idx >> 6, j = idx & 63;
    A[(size_t)b * KD + HD + j] = (j < DD) ? f2bf(st[j]) : (u16)0;
}

// ---------------- output projection, thread-per-(row,d), PAIRED ------------
// Spill-free (round-16 proven: ~10us/pair, WRITE back to ~1MB).
__global__ __launch_bounds__(256, 8)
void outproj_pd(const u16* __restrict__ H0, const u16* __restrict__ H1,
                const u16* __restrict__ Wb, const float* __restrict__ bout,
                float* __restrict__ xr, int t)
{
    int gid = blockIdx.x * 256 + threadIdx.x;   // BB*16
    int b = gid >> 4;
    int d = gid & 15;
    const bool act = (d < DD);
    const int dc = act ? d : 0;
    const u16* h0 = H0 + (size_t)b * KD;
    const u16* h1 = H1 + (size_t)b * KD;
    const u16* w  = Wb + dc * HD;
    float a0 = 0.f, a1 = 0.f;
    for (int k = 0; k < HD; k += 8) {
        bf16x8 wv = *(const bf16x8*)&w[k];
        bf16x8 v0 = *(const bf16x8*)&h0[k];
        bf16x8 v1 = *(const bf16x8*)&h1[k];
#pragma unroll
        for (int q = 0; q < 8; ++q) {
            float wf = bf2f((u16)wv[q]);
            a0 += bf2f((u16)v0[q]) * wf;
            a1 += bf2f((u16)v1[q]) * wf;
        }
    }
    if (act) {
        xr[((size_t)b * TT + t) * DD + d]     = a0 + bout[d];
        xr[((size_t)b * TT + t + 1) * DD + d] = a1 + bout[d];
    }
}

// ---------------- launch ----------------
extern "C" void kernel_launch(void* const* d_in, const int* in_sizes, int n_in,
                              void* d_out, int out_size, void* d_ws, size_t ws_size,
                              hipStream_t stream)
{
    const float* x    = (const float*)d_in[0];
    const int*   lens = (const int*)d_in[1];
    const float* eps  = (const float*)d_in[2];
    const float* Wihe = (const float*)d_in[3];
    const float* Whhe = (const float*)d_in[4];
    const float* be   = (const float*)d_in[5];
    const float* Wmu  = (const float*)d_in[6];
    const float* bmu  = (const float*)d_in[7];
    const float* Wlv  = (const float*)d_in[8];
    const float* blv  = (const float*)d_in[9];
    const float* Wh0  = (const float*)d_in[10];
    const float* bh0  = (const float*)d_in[11];
    const float* Wc0  = (const float*)d_in[12];
    const float* bc0  = (const float*)d_in[13];
    const float* st   = (const float*)d_in[14];
    const float* Wihd = (const float*)d_in[15];
    const float* Whhd = (const float*)d_in[16];
    const float* bd   = (const float*)d_in[17];
    const float* Wout = (const float*)d_in[18];
    const float* bout = (const float*)d_in[19];
    float* out = (float*)d_out;

    char* ws = (char*)d_ws;
    size_t o = 0;
    u16*   WCE = (u16*)(ws + o); o += (size_t)2048 * KE * 2;   // 2,359,296
    u16*   WCD = (u16*)(ws + o); o += (size_t)4096 * KD * 2;   // 8,912,896
    u16*   WMV = (u16*)(ws + o); o += (size_t)256 * 512 * 2;   // 262,144
    u16*   WHC = (u16*)(ws + o); o += (size_t)2048 * 128 * 2;  // 524,288
    u16*   WOB = (u16*)(ws + o); o += 32768;
    u16*   AE0 = (u16*)(ws + o); o += (size_t)BB * KE * 2;     // 9,437,184
    u16*   AE1 = (u16*)(ws + o); o += (size_t)BB * KE * 2;
    u16*   AD0 = (u16*)(ws + o); o += (size_t)BB * KD * 2;     // 17,825,792
    u16*   AD1 = (u16*)(ws + o); o += (size_t)BB * KD * 2;
    float* CE  = (float*)(ws + o); o += (size_t)BB * HE * 4;   // 16,777,216
    float* CD  = (float*)(ws + o); o += (size_t)BB * HD * 4;   // 33,554,432
    u16*   HNb = (u16*)(ws + o); o += (size_t)BB * HE * 2;     // 8,388,608
    float* MV  = (float*)(ws + o); o += (size_t)BB * 256 * 4;  // 8,388,608
    u16*   Zbf = (u16*)(ws + o); o += (size_t)BB * ZZ * 2;     // 2,097,152
    float* HC  = (float*)(ws + o); o += (size_t)BB * 2048 * 4; // 67,108,864
    // total ~203 MB

    prep_wg<<<(2048 * KE + 255) / 256, 256, 0, stream>>>(Whhe, Wihe, WCE, HE, KE, 2048 * KE);
    prep_wg<<<(4096 * KD + 255) / 256, 256, 0, stream>>>(Whhd, Wihd, WCD, HD, KD, 4096 * KD);
    prep_cat<<<(256 * 512 + 255) / 256, 256, 0, stream>>>(Wmu, Wlv, WMV, ZZ, HE, 256 * 512);
    prep_cat<<<(2048 * 128 + 255) / 256, 256, 0, stream>>>(Wh0, Wc0, WHC, HD, ZZ, 2048 * 128);
    prep_bf<<<(12 * HD + 255) / 256, 256, 0, stream>>>(Wout, WOB, 12 * HD);
    init_enc<<<(BB * KE) / 256, 256, 0, stream>>>(AE0, CE, x);
    // zero the pad columns of the ping buffers (epilogue never writes them)
    zero_pads<<<(BB * 52 + 255) / 256, 256, 0, stream>>>(AE1, KE, HE + DD, 52, BB * 52);
    zero_pads<<<(BB * 52 + 255) / 256, 256, 0, stream>>>(AD1, KD, HD + DD, 52, BB * 52);

    u16* AE[2] = {AE0, AE1};
    for (int t = 0; t < TT; ++t) {
        gemm_fused<1><<<dim3(BB / 128, 2048 / 256), 256, 0, stream>>>(
            AE[t & 1], WCE, nullptr, 2048, KE, HE, CE, AE[1 - (t & 1)],
            be, lens, HNb, x, t);
    }

    gemm_fused<0><<<dim3(BB / 128, 1), 256, 0, stream>>>(
        HNb, WMV, MV, 256, 512, 0, nullptr, nullptr, nullptr, nullptr, nullptr, nullptr, 0);
    z_comp<<<(BB * ZZ) / 256, 256, 0, stream>>>(MV, bmu, blv, eps, out, Zbf);
    gemm_fused<0><<<dim3(BB / 128, 2048 / 256), 256, 0, stream>>>(
        Zbf, WHC, HC, 2048, 128, 0, nullptr, nullptr, nullptr, nullptr, nullptr, nullptr, 0);
    hc_init<<<(BB * HD) / 256, 256, 0, stream>>>(HC, bh0, bc0, AD0, CD);
    init_dec<<<(BB * 64) / 256, 256, 0, stream>>>(AD0, st);

    u16* AD[2] = {AD0, AD1};
    for (int t = 0; t < TT; t += 2) {
        // gemm t: reads AD[t&1] (h_{t-1}), writes AD[1-(t&1)] (h_t)
        gemm_fused<2><<<dim3(BB / 128, 4096 / 256), 256, 0, stream>>>(
            AD[t & 1], WCD, nullptr, 4096, KD, HD, CD, AD[1 - (t & 1)],
            bd, nullptr, nullptr, x, t);
        // gemm t+1: reads AD[1-(t&1)] (h_t), writes AD[t&1] (h_{t+1})
        gemm_fused<2><<<dim3(BB / 128, 4096 / 256), 256, 0, stream>>>(
            AD[1 - (t & 1)], WCD, nullptr, 4096, KD, HD, CD, AD[t & 1],
            bd, nullptr, nullptr, x, t + 1);
        // both h_t (AD[1-(t&1)]) and h_{t+1} (AD[t&1]) are live -> one launch
        outproj_pd<<<(BB * 16) / 256, 256, 0, stream>>>(
            AD[1 - (t & 1)], AD[t & 1], WOB, bout, out, t);
    }
}